// Round 21
// baseline (232.769 us; speedup 1.0000x reference)
//
#include <hip/hip_runtime.h>
#include <hip/hip_bf16.h>
#include <cstdint>
#include <cstddef>

#define TOK   2048
#define DIMSZ 2048
#define D3    6144
#define NHEAD 32
#define HDIM  64
#define NSPLIT 2
#define KVCHUNK (TOK/NSPLIT)

typedef __attribute__((ext_vector_type(8)))  short bf16x8;
typedef __attribute__((ext_vector_type(8)))  unsigned short u16x8;
typedef __attribute__((ext_vector_type(4)))  float f32x4;
typedef __attribute__((ext_vector_type(16))) float f32x16;
typedef __attribute__((ext_vector_type(2)))  unsigned uint2v;

__device__ __forceinline__ float bf2f(unsigned short u){
  return __uint_as_float(((unsigned)u) << 16);
}
__device__ __forceinline__ unsigned short f2bf(float f){
  unsigned u = __float_as_uint(f);
  u += 0x7fffu + ((u >> 16) & 1u);   // RNE
  return (unsigned short)(u >> 16);
}
// HW packed f32->bf16 RNE (register-only asm: no hazard-recognizer exposure)
__device__ __forceinline__ unsigned pack2bf(float a, float b){
  unsigned r;
  asm("v_cvt_pk_bf16_f32 %0, %1, %2" : "=v"(r) : "v"(a), "v"(b));
  return r;
}
// lane[i] (i>=32) of a  <->  lane[i-32] of b   (one op fills two B-frag words)
__device__ __forceinline__ uint2v plswap(unsigned a, unsigned b){
  return __builtin_amdgcn_permlane32_swap(a, b, false, false);
}
__device__ __forceinline__ void gload16(const void* g, void* l){
  __builtin_amdgcn_global_load_lds(
      (const __attribute__((address_space(1))) void*)g,
      (__attribute__((address_space(3))) void*)l, 16, 0, 0);
}
// builtin MFMA only (inline-asm MFMA is opaque to GCNHazardRecognizer — r2-r4 bug)
__device__ __forceinline__ void mfma16(bf16x8 a, bf16x8 b, f32x4& c){
  c = __builtin_amdgcn_mfma_f32_16x16x32_bf16(a, b, c, 0, 0, 0);
}
__device__ __forceinline__ void mfma32(bf16x8 a, bf16x8 b, f32x16& c){
  c = __builtin_amdgcn_mfma_f32_32x32x16_bf16(a, b, c, 0, 0, 0);
}

// ---------------- prep kernels ----------------

// gate (per-head sigmoid) + fused fp32->bf16 row convert (row is cache-hot)
__global__ __launch_bounds__(256) void gate_kernel(
    const float* __restrict__ x, const float* __restrict__ Wg,
    const float* __restrict__ bg, float* __restrict__ gate,
    unsigned short* __restrict__ xbf){
  int n = blockIdx.x;
  int t = threadIdx.x;
  int h = t >> 3, j = t & 7;
  const float4* xr = (const float4*)(x + (size_t)n*DIMSZ);
  {
    float4 a = xr[t*2], b = xr[t*2+1];
    u16x8 o;
    o[0]=f2bf(a.x); o[1]=f2bf(a.y); o[2]=f2bf(a.z); o[3]=f2bf(a.w);
    o[4]=f2bf(b.x); o[5]=f2bf(b.y); o[6]=f2bf(b.z); o[7]=f2bf(b.w);
    *(u16x8*)(xbf + (size_t)n*DIMSZ + t*8) = o;
  }
  const float4* wr = (const float4*)(Wg + (size_t)h*DIMSZ);
  float s = 0.f;
  #pragma unroll 8
  for (int i=0;i<64;i++){
    float4 a = xr[j + i*8], b = wr[j + i*8];
    s += a.x*b.x + a.y*b.y + a.z*b.z + a.w*b.w;
  }
  s += __shfl_xor(s,1); s += __shfl_xor(s,2); s += __shfl_xor(s,4);
  if (j==0) gate[(size_t)h*TOK + n] = 2.f/(1.f + __expf(-(s + bg[h])));
}

// fp32 (R x C) -> bf16 (C x R); 64x64 tiles, float4 loads, u16x8 stores
__global__ __launch_bounds__(256) void transpose_cvt_kernel(
    const float* __restrict__ in, unsigned short* __restrict__ out, int R, int C){
  __shared__ unsigned short tile[64][65];
  const int r0 = blockIdx.x*64, c0 = blockIdx.y*64;
  const int t = threadIdx.x;
  {
    const int r = t >> 2, cc = (t & 3) * 16;
    const float4* src = (const float4*)(in + (size_t)(r0+r)*C + c0 + cc);
    #pragma unroll
    for (int q=0;q<4;q++){
      float4 v = src[q];
      tile[r][cc+q*4+0]=f2bf(v.x); tile[r][cc+q*4+1]=f2bf(v.y);
      tile[r][cc+q*4+2]=f2bf(v.z); tile[r][cc+q*4+3]=f2bf(v.w);
    }
  }
  __syncthreads();
  {
    const int c = t >> 2, rc = (t & 3) * 16;
    unsigned short* dst = out + (size_t)(c0+c)*R + r0 + rc;
    u16x8 o0, o1;
    #pragma unroll
    for (int q=0;q<8;q++){ o0[q] = tile[rc+q][c]; o1[q] = tile[rc+8+q][c]; }
    *(u16x8*)dst       = o0;
    *(u16x8*)(dst + 8) = o1;
  }
}

// ---------------- GEMM v3: m97 tile + TRIPLE-buffer LDS + counted vmcnt (T4) + raw s_barrier,
// ---------------- T2 slot swizzle, T1 XCD swizzle. NO setprio: m190 measured setprio as
// ---------------- slightly negative on barrier-lockstep GEMM waves (attn keeps it). ----------------
// C[M,N] = A[M,K] @ Bt[N,K]^T
// MODE 0: bf16 out + bias.   MODE 2: K-split partial (gridDim.z planes), bf16, no bias.
template<int MODE>
__global__ __launch_bounds__(256) void gemm_bt(
    const unsigned short* __restrict__ A, const unsigned short* __restrict__ Bt,
    const float* __restrict__ bias,
    unsigned short* __restrict__ Cbf,
    int M, int N, int K)
{
  __shared__ __align__(16) unsigned short ldsA[3][128*32];
  __shared__ __align__(16) unsigned short ldsB[3][128*32];   // 48 KB
  const int tid  = threadIdx.x;
  const int w    = tid >> 6;
  const int lane = tid & 63;
  const int g    = lane >> 4;
  const int li   = lane & 15;

  // T1: bijective XCD swizzle (per z-plane; nwg % 8 == 0 for all uses)
  const int gx = gridDim.x;
  const int nwg = gx * gridDim.y;
  const int lin = blockIdx.x + gx * blockIdx.y;
  const int q8  = nwg >> 3;
  const int nl  = (lin & 7) * q8 + (lin >> 3);
  const int bm  = (nl % gx) * 128;
  const int bn  = (nl / gx) * 128;

  const int wm   = (w >> 1) * 64;
  const int wn   = (w & 1) * 64;

  const int KS  = (MODE==2) ? (K / (int)gridDim.z) : K;
  const int kt0 = (MODE==2) ? (blockIdx.z * KS) : 0;
  const int nsteps = KS >> 5;

  f32x4 acc[4][4];
  #pragma unroll
  for (int i=0;i<4;i++)
    #pragma unroll
    for (int j=0;j<4;j++)
      acc[i][j] = (f32x4){0.f,0.f,0.f,0.f};

  const int srow = lane >> 2;                                  // 0..15 (row within 16-row chunk)
  const int scb  = ((lane & 3) ^ ((srow >> 1) & 3)) * 16;      // swizzled source col (bytes)
  const int rsw  = (li >> 1) & 3;                              // read-side slot xor

  auto stage = [&](int buf, int step){
    const int kt = kt0 + step*32;
    #pragma unroll
    for (int i=0;i<2;i++){
      const int chunk = i*4 + w;
      const int row   = chunk*16 + srow;
      gload16((const char*)A  + ((size_t)(bm+row)*K + kt)*2 + scb, (char*)ldsA[buf] + chunk*1024);
      gload16((const char*)Bt + ((size_t)(bn+row)*K + kt)*2 + scb, (char*)ldsB[buf] + chunk*1024);
    }
  };

  stage(0, 0);
  stage(1, 1);
  for (int s = 0; s < nsteps; ++s){
    if (s + 1 < nsteps){
      asm volatile("s_waitcnt vmcnt(4)" ::: "memory");
    } else {
      asm volatile("s_waitcnt vmcnt(0)" ::: "memory");
    }
    __builtin_amdgcn_sched_barrier(0);
    __builtin_amdgcn_s_barrier();
    __builtin_amdgcn_sched_barrier(0);
    if (s + 2 < nsteps) stage((s+2)%3, s+2);
    const int cur = s % 3;
    bf16x8 af[4], bfr[4];
    #pragma unroll
    for (int mi=0;mi<4;mi++)
      af[mi] = *(const bf16x8*)((const char*)ldsA[cur] + (wm + mi*16 + li)*64 + ((g ^ rsw)*16));
    #pragma unroll
    for (int ni=0;ni<4;ni++)
      bfr[ni] = *(const bf16x8*)((const char*)ldsB[cur] + (wn + ni*16 + li)*64 + ((g ^ rsw)*16));
    #pragma unroll
    for (int mi=0;mi<4;mi++)
      #pragma unroll
      for (int ni=0;ni<4;ni++)
        mfma16(af[mi], bfr[ni], acc[mi][ni]);
  }

  const size_t zoff = (MODE==2) ? ((size_t)blockIdx.z * M * N) : 0;
  #pragma unroll
  for (int ni=0;ni<4;ni++){
    const int col = bn + wn + ni*16 + li;
    const float bv = (MODE==0) ? bias[col] : 0.f;
    #pragma unroll
    for (int mi=0;mi<4;mi++){
      #pragma unroll
      for (int r=0;r<4;r++){
        const int row = bm + wm + mi*16 + g*4 + r;
        Cbf[zoff + (size_t)row*N + col] = f2bf(acc[mi][ni][r] + bv);
      }
    }
  }
}

// ---------------- out-proj epilogue: out = residual + (p0 + p1 + bias) * gate_mod ----------------
// partials are bf16 planes (4 elements = uint2 per thread-quad)
__global__ __launch_bounds__(256) void out_combine_kernel(
    const unsigned short* __restrict__ part, const float* __restrict__ bias,
    const float* __restrict__ residual, const float* __restrict__ gate_mod,
    float* __restrict__ out)
{
  const size_t idx = (size_t)blockIdx.x*256 + threadIdx.x;      // 4-element index
  const int col4 = (int)(idx & (DIMSZ/4 - 1));
  const uint2 ua = ((const uint2*)part)[idx];
  const uint2 ub = ((const uint2*)part)[idx + (size_t)TOK*DIMSZ/4];
  const float4 r = ((const float4*)residual)[idx];
  const float4 bv = ((const float4*)bias)[col4];
  const float4 gm = ((const float4*)gate_mod)[col4];
  float4 o;
  o.x = r.x + (bf2f((unsigned short)ua.x)       + bf2f((unsigned short)ub.x)       + bv.x) * gm.x;
  o.y = r.y + (bf2f((unsigned short)(ua.x>>16)) + bf2f((unsigned short)(ub.x>>16)) + bv.y) * gm.y;
  o.z = r.z + (bf2f((unsigned short)ua.y)       + bf2f((unsigned short)ub.y)       + bv.z) * gm.z;
  o.w = r.w + (bf2f((unsigned short)(ua.y>>16)) + bf2f((unsigned short)(ub.y>>16)) + bv.w) * gm.w;
  ((float4*)out)[idx] = o;
}

// ---------------- RMSNorm + RoPE; Q scaled by (1/8)*log2(e) so softmax runs in exp2 domain ----------------
__global__ __launch_bounds__(256) void norm_rope_kernel(
    const unsigned short* __restrict__ qkv,
    const float* __restrict__ nqw, const float* __restrict__ nkw,
    const float* __restrict__ rc, const float* __restrict__ rsn,
    unsigned short* __restrict__ Q, unsigned short* __restrict__ Ko)
{
  const int n = blockIdx.x, t = threadIdx.x;
  __shared__ float red[2][4];
  #pragma unroll
  for (int qk=0; qk<2; qk++){
    const unsigned short* row = qkv + (size_t)n*D3 + qk*DIMSZ;
    u16x8 v = *(const u16x8*)(row + t*8);
    float f[8]; float ss = 0.f;
    #pragma unroll
    for (int j=0;j<8;j++){ f[j] = bf2f(v[j]); ss += f[j]*f[j]; }
    #pragma unroll
    for (int msk=1; msk<64; msk<<=1) ss += __shfl_xor(ss, msk);
    if ((t&63)==0) red[qk][t>>6] = ss;
    __syncthreads();
    const float rs = rsqrtf((red[qk][0]+red[qk][1]+red[qk][2]+red[qk][3]) * (1.0f/2048.f) + 1e-6f);
    const int d = t*8, hd = d&63, h = d>>6;
    const int pd = (hd<32) ? d+32 : d-32;
    u16x8 pv = *(const u16x8*)(row + pd);
    const float* wv = qk ? nkw : nqw;
    const float4 wv0 = *(const float4*)(wv + d),      wv1 = *(const float4*)(wv + d + 4);
    const float4 pw0 = *(const float4*)(wv + pd),     pw1 = *(const float4*)(wv + pd + 4);
    const float4 cs0 = *(const float4*)(rc + n*64 + hd),  cs1 = *(const float4*)(rc + n*64 + hd + 4);
    const float4 sn0 = *(const float4*)(rsn + n*64 + hd), sn1 = *(const float4*)(rsn + n*64 + hd + 4);
    const float wvv[8] = {wv0.x,wv0.y,wv0.z,wv0.w, wv1.x,wv1.y,wv1.z,wv1.w};
    const float pwv[8] = {pw0.x,pw0.y,pw0.z,pw0.w, pw1.x,pw1.y,pw1.z,pw1.w};
    const float csv[8] = {cs0.x,cs0.y,cs0.z,cs0.w, cs1.x,cs1.y,cs1.z,cs1.w};
    const float snv[8] = {sn0.x,sn0.y,sn0.z,sn0.w, sn1.x,sn1.y,sn1.z,sn1.w};
    const float scl = qk ? 1.f : (0.125f * 1.44269504088896340736f);
    const float sgn = (hd<32) ? -1.f : 1.f;
    u16x8 ov;
    #pragma unroll
    for (int j=0;j<8;j++){
      const float a = f[j]*rs*wvv[j];
      const float b = bf2f(pv[j])*rs*pwv[j];
      ov[j] = f2bf((a*csv[j] + sgn*b*snv[j])*scl);
    }
    unsigned short* dst = (qk ? Ko : Q) + ((size_t)h*TOK + n)*HDIM + hd;
    *(u16x8*)dst = ov;
  }
}

// ---------------- V transpose per head: qkv v-part (N,HD slice) -> Vt (H,HD,N) ----------------
__global__ __launch_bounds__(256) void v_transpose_kernel(
    const unsigned short* __restrict__ qkv, unsigned short* __restrict__ Vt){
  const int h = blockIdx.y, n0 = blockIdx.x*64;
  __shared__ unsigned short tile[64][65];
  const int t = threadIdx.x;
  const int i = t>>2, j0 = (t&3)*16;
  const unsigned short* src = qkv + (size_t)(n0+i)*D3 + 2*DIMSZ + h*HDIM + j0;
  #pragma unroll
  for (int q=0;q<16;q++) tile[i][j0+q] = src[q];
  __syncthreads();
  unsigned short* dst = Vt + ((size_t)h*HDIM + i)*TOK + n0 + j0;
  #pragma unroll
  for (int q=0;q<16;q++) dst[q] = tile[j0+q][i];
}

// ---------------- Flash attention: KV-split-2, NO max tracking, launch_bounds(256,4) ----------------
__global__ __launch_bounds__(256, 4) void flash_kernel(
    const unsigned short* __restrict__ Q, const unsigned short* __restrict__ K,
    const unsigned short* __restrict__ Vt,
    unsigned short* __restrict__ Opart, float* __restrict__ lpart)
{
  __shared__ __align__(16) unsigned short ldsK[2][64*64];
  __shared__ __align__(16) unsigned short ldsV[2][64*64];
  const int tid = threadIdx.x;
  const int w = tid >> 6, lane = tid & 63;
  const int q5 = lane & 31, hi = lane >> 5;
  const int sp = blockIdx.y & (NSPLIT-1), h = blockIdx.y >> 1;
  const int q0 = blockIdx.x * 128;
  const int qrow = q0 + w*32 + q5;
  const int kt0 = sp * KVCHUNK;

  const unsigned short* Qh = Q + (size_t)h*TOK*HDIM;
  bf16x8 qf[4];
  #pragma unroll
  for (int ks=0; ks<4; ks++)
    qf[ks] = *(const bf16x8*)(Qh + (size_t)qrow*HDIM + ks*16 + hi*8);

  f32x16 o0 = {}, o1 = {};
  float l_ = 0.f;

  const char* Kh = (const char*)(K  + (size_t)h*TOK*HDIM);   // 128B rows
  const char* Vh = (const char*)(Vt + (size_t)h*HDIM*TOK);   // 4096B rows
  const int srow = lane >> 3;                  // staging row mod 8
  const int scb  = ((lane & 7) ^ srow) * 16;   // pre-swizzled source column
  const int xr   = (lane & 7) << 4;            // read-side xor (row&7 == lane&7)

  auto stage = [&](int buf, int kt){
    #pragma unroll
    for (int i=0;i<2;i++){
      const int chunk = i*4 + w;
      const int row = chunk*8 + srow;
      gload16(Kh + (size_t)(kt+row)*128 + scb, (char*)ldsK[buf] + chunk*1024);
      gload16(Vh + (size_t)row*4096 + (size_t)kt*2 + scb, (char*)ldsV[buf] + chunk*1024);
    }
  };

  stage(0, kt0);
  int cur = 0;
  for (int kt = kt0; kt < kt0 + KVCHUNK; kt += 64){
    __syncthreads();
    if (kt + 64 < kt0 + KVCHUNK) stage(cur^1, kt + 64);

    f32x16 s0 = {}, s1 = {};
    __builtin_amdgcn_s_setprio(1);
    #pragma unroll
    for (int ks=0; ks<4; ks++){
      const int cb = (ks*32 + hi*16) ^ xr;
      const bf16x8 kb0 = *(const bf16x8*)((const char*)ldsK[cur] + q5*128 + cb);
      const bf16x8 kb1 = *(const bf16x8*)((const char*)ldsK[cur] + (32+q5)*128 + cb);
      mfma32(kb0, qf[ks], s0);
      mfma32(kb1, qf[ks], s1);
    }
    __builtin_amdgcn_s_setprio(0);

    // P = exp2(S) directly (no running max); lane-local l accumulation
    unsigned pw[16];
    #pragma unroll
    for (int i=0;i<8;i++){
      const float pa = exp2f(s0[2*i]);
      const float pb = exp2f(s0[2*i+1]);
      l_ += pa + pb;
      pw[i] = pack2bf(pa, pb);
    }
    #pragma unroll
    for (int i=0;i<8;i++){
      const float pa = exp2f(s1[2*i]);
      const float pb = exp2f(s1[2*i+1]);
      l_ += pa + pb;
      pw[8+i] = pack2bf(pa, pb);
    }

    __builtin_amdgcn_s_setprio(1);
    #pragma unroll
    for (int ks2=0; ks2<4; ks2++){
      const int b = 4*ks2;
      const uint2v r0 = plswap(pw[b],   pw[b+2]);
      const uint2v r1 = plswap(pw[b+1], pw[b+3]);
      union { unsigned u[4]; bf16x8 v; } pf;
      pf.u[0] = r0[0]; pf.u[1] = r1[0]; pf.u[2] = r0[1]; pf.u[3] = r1[1];
      const int cb = (ks2*32 + hi*16) ^ xr;
      const bf16x8 vb0 = *(const bf16x8*)((const char*)ldsV[cur] + q5*128 + cb);
      const bf16x8 vb1 = *(const bf16x8*)((const char*)ldsV[cur] + (32+q5)*128 + cb);
      mfma32(vb0, pf.v, o0);
      mfma32(vb1, pf.v, o1);
    }
    __builtin_amdgcn_s_setprio(0);
    cur ^= 1;
  }

  const float lt = l_ + __shfl_xor(l_, 32);
  const size_t prow = ((size_t)(sp*NHEAD + h)*TOK + qrow);
  if (hi == 0) lpart[prow] = lt;
  unsigned short* orow = Opart + prow*HDIM;
  #pragma unroll
  for (int j=0;j<4;j++){
    const int d0 = 8*j + 4*hi;
    uint2 v0, v1;
    v0.x = pack2bf(o0[4*j],   o0[4*j+1]);
    v0.y = pack2bf(o0[4*j+2], o0[4*j+3]);
    v1.x = pack2bf(o1[4*j],   o1[4*j+1]);
    v1.y = pack2bf(o1[4*j+2], o1[4*j+3]);
    *(uint2*)(orow + d0)      = v0;
    *(uint2*)(orow + 32 + d0) = v1;
  }
}

// ---------------- split combine (2 splits, no-max: plain sums) ----------------
__global__ __launch_bounds__(256) void combine_kernel(
    const unsigned short* __restrict__ Opart, const float* __restrict__ lpart,
    const float* __restrict__ gate, unsigned short* __restrict__ attn_out)
{
  const int tid = threadIdx.x;
  const int R = blockIdx.x*8 + (tid >> 5);       // (h, q) row index
  const int l32 = tid & 31;                      // element pair index
  const int h = R >> 11, q = R & (TOK-1);

  const float* lp = lpart + (size_t)h*TOK + q;
  const size_t lstr = (size_t)NHEAD*TOK;
  const float L = lp[0] + lp[lstr];

  const unsigned* Op = (const unsigned*)Opart;
  const size_t b32 = ((size_t)h*TOK + q)*32 + l32;
  const size_t str = (size_t)NHEAD*TOK*32;
  const unsigned u0 = Op[b32], u1 = Op[b32+str];

  const float oa = bf2f((unsigned short)u0) + bf2f((unsigned short)u1);
  const float ob = bf2f((unsigned short)(u0>>16)) + bf2f((unsigned short)(u1>>16));

  const float gv = gate[(size_t)h*TOK + q];
  const float sc = gv / L;
  const unsigned word = (unsigned)f2bf(oa*sc) | ((unsigned)f2bf(ob*sc) << 16);
  *(unsigned*)(attn_out + (size_t)q*DIMSZ + h*HDIM + l32*2) = word;
}

// ---------------- launch ----------------

extern "C" void kernel_launch(void* const* d_in, const int* in_sizes, int n_in,
                              void* d_out, int out_size, void* d_ws, size_t ws_size,
                              hipStream_t stream)
{
  const float* x        = (const float*)d_in[0];
  const float* W_qkv    = (const float*)d_in[1];
  const float* b_qkv    = (const float*)d_in[2];
  const float* nq_w     = (const float*)d_in[3];
  const float* nk_w     = (const float*)d_in[4];
  const float* W_gate   = (const float*)d_in[5];
  const float* b_gate   = (const float*)d_in[6];
  const float* W_out    = (const float*)d_in[7];
  const float* b_out    = (const float*)d_in[8];
  const float* rope_cos = (const float*)d_in[9];
  const float* rope_sin = (const float*)d_in[10];
  const float* residual = (const float*)d_in[11];
  const float* gate_mod = (const float*)d_in[12];
  float* out = (float*)d_out;

  char* p = (char*)d_ws;
  auto take = [&](size_t b)->char*{ char* q = p; p += (b + 255) & ~(size_t)255; return q; };
  unsigned short* x_bf   = (unsigned short*)take((size_t)TOK*DIMSZ*2);
  unsigned short* WqkvT  = (unsigned short*)take((size_t)D3*DIMSZ*2);
  unsigned short* WoutT  = (unsigned short*)take((size_t)DIMSZ*DIMSZ*2);
  unsigned short* qkv    = (unsigned short*)take((size_t)TOK*D3*2);
  unsigned short* Qb     = (unsigned short*)take((size_t)NHEAD*TOK*HDIM*2);
  unsigned short* Kb     = (unsigned short*)take((size_t)NHEAD*TOK*HDIM*2);
  unsigned short* Vtb    = (unsigned short*)take((size_t)NHEAD*HDIM*TOK*2);
  unsigned short* attn_g = (unsigned short*)take((size_t)TOK*DIMSZ*2);
  float*          gateb  = (float*)take((size_t)NHEAD*TOK*4);
  unsigned short* Opart  = (unsigned short*)take((size_t)NSPLIT*NHEAD*TOK*HDIM*2);
  float*          lpart  = (float*)take((size_t)NSPLIT*NHEAD*TOK*4);
  // out-proj K-split bf16 partials (2 x M x N x 2B = 16.8 MB) reuse Opart's space
  // (NSPLIT=2 Opart is exactly 16.8 MB; dead after combine_kernel).
  unsigned short* oproj  = Opart;

  gate_kernel<<<TOK, 256, 0, stream>>>(x, W_gate, b_gate, gateb, x_bf);
  transpose_cvt_kernel<<<dim3(DIMSZ/64, D3/64),   256, 0, stream>>>(W_qkv, WqkvT, DIMSZ, D3);
  transpose_cvt_kernel<<<dim3(DIMSZ/64, DIMSZ/64),256, 0, stream>>>(W_out, WoutT, DIMSZ, DIMSZ);
  gemm_bt<0><<<dim3(TOK/128, D3/128), 256, 0, stream>>>(
      x_bf, WqkvT, b_qkv, qkv, TOK, D3, DIMSZ);
  norm_rope_kernel<<<TOK, 256, 0, stream>>>(qkv, nq_w, nk_w, rope_cos, rope_sin, Qb, Kb);
  v_transpose_kernel<<<dim3(TOK/64, NHEAD), 256, 0, stream>>>(qkv, Vtb);
  flash_kernel<<<dim3(TOK/128, NHEAD*NSPLIT), 256, 0, stream>>>(Qb, Kb, Vtb, Opart, lpart);
  combine_kernel<<<NHEAD*TOK/8, 256, 0, stream>>>(Opart, lpart, gateb, attn_g);
  gemm_bt<2><<<dim3(TOK/128, DIMSZ/128, 2), 256, 0, stream>>>(
      attn_g, WoutT, b_out, oproj, TOK, DIMSZ, DIMSZ);
  out_combine_kernel<<<TOK*DIMSZ/1024, 256, 0, stream>>>(
      oproj, b_out, residual, gate_mod, out);
}

// Round 22
// 231.658 us; speedup vs baseline: 1.0048x; 1.0048x over previous
//
#include <hip/hip_runtime.h>
#include <hip/hip_bf16.h>
#include <cstdint>
#include <cstddef>

#define TOK   2048
#define DIMSZ 2048
#define D3    6144
#define NHEAD 32
#define HDIM  64
#define NSPLIT 2
#define KVCHUNK (TOK/NSPLIT)

typedef __attribute__((ext_vector_type(8)))  short bf16x8;
typedef __attribute__((ext_vector_type(8)))  unsigned short u16x8;
typedef __attribute__((ext_vector_type(4)))  float f32x4;
typedef __attribute__((ext_vector_type(16))) float f32x16;
typedef __attribute__((ext_vector_type(2)))  unsigned uint2v;

__device__ __forceinline__ float bf2f(unsigned short u){
  return __uint_as_float(((unsigned)u) << 16);
}
__device__ __forceinline__ unsigned short f2bf(float f){
  unsigned u = __float_as_uint(f);
  u += 0x7fffu + ((u >> 16) & 1u);   // RNE
  return (unsigned short)(u >> 16);
}
// HW packed f32->bf16 RNE (register-only asm: no hazard-recognizer exposure)
__device__ __forceinline__ unsigned pack2bf(float a, float b){
  unsigned r;
  asm("v_cvt_pk_bf16_f32 %0, %1, %2" : "=v"(r) : "v"(a), "v"(b));
  return r;
}
// lane[i] (i>=32) of a  <->  lane[i-32] of b   (one op fills two B-frag words)
__device__ __forceinline__ uint2v plswap(unsigned a, unsigned b){
  return __builtin_amdgcn_permlane32_swap(a, b, false, false);
}
__device__ __forceinline__ void gload16(const void* g, void* l){
  __builtin_amdgcn_global_load_lds(
      (const __attribute__((address_space(1))) void*)g,
      (__attribute__((address_space(3))) void*)l, 16, 0, 0);
}
// builtin MFMA only (inline-asm MFMA is opaque to GCNHazardRecognizer — r2-r4 bug)
__device__ __forceinline__ void mfma16(bf16x8 a, bf16x8 b, f32x4& c){
  c = __builtin_amdgcn_mfma_f32_16x16x32_bf16(a, b, c, 0, 0, 0);
}
__device__ __forceinline__ void mfma32(bf16x8 a, bf16x8 b, f32x16& c){
  c = __builtin_amdgcn_mfma_f32_32x32x16_bf16(a, b, c, 0, 0, 0);
}

// ---------------- prep kernels ----------------

// gate (per-head sigmoid) + fused fp32->bf16 row convert (row is cache-hot)
__global__ __launch_bounds__(256) void gate_kernel(
    const float* __restrict__ x, const float* __restrict__ Wg,
    const float* __restrict__ bg, float* __restrict__ gate,
    unsigned short* __restrict__ xbf){
  int n = blockIdx.x;
  int t = threadIdx.x;
  int h = t >> 3, j = t & 7;
  const float4* xr = (const float4*)(x + (size_t)n*DIMSZ);
  {
    float4 a = xr[t*2], b = xr[t*2+1];
    u16x8 o;
    o[0]=f2bf(a.x); o[1]=f2bf(a.y); o[2]=f2bf(a.z); o[3]=f2bf(a.w);
    o[4]=f2bf(b.x); o[5]=f2bf(b.y); o[6]=f2bf(b.z); o[7]=f2bf(b.w);
    *(u16x8*)(xbf + (size_t)n*DIMSZ + t*8) = o;
  }
  const float4* wr = (const float4*)(Wg + (size_t)h*DIMSZ);
  float s = 0.f;
  #pragma unroll 8
  for (int i=0;i<64;i++){
    float4 a = xr[j + i*8], b = wr[j + i*8];
    s += a.x*b.x + a.y*b.y + a.z*b.z + a.w*b.w;
  }
  s += __shfl_xor(s,1); s += __shfl_xor(s,2); s += __shfl_xor(s,4);
  if (j==0) gate[(size_t)h*TOK + n] = 2.f/(1.f + __expf(-(s + bg[h])));
}

// fp32 (R x C) -> bf16 (C x R); 64x64 tiles, float4 loads, u16x8 stores
__global__ __launch_bounds__(256) void transpose_cvt_kernel(
    const float* __restrict__ in, unsigned short* __restrict__ out, int R, int C){
  __shared__ unsigned short tile[64][65];
  const int r0 = blockIdx.x*64, c0 = blockIdx.y*64;
  const int t = threadIdx.x;
  {
    const int r = t >> 2, cc = (t & 3) * 16;
    const float4* src = (const float4*)(in + (size_t)(r0+r)*C + c0 + cc);
    #pragma unroll
    for (int q=0;q<4;q++){
      float4 v = src[q];
      tile[r][cc+q*4+0]=f2bf(v.x); tile[r][cc+q*4+1]=f2bf(v.y);
      tile[r][cc+q*4+2]=f2bf(v.z); tile[r][cc+q*4+3]=f2bf(v.w);
    }
  }
  __syncthreads();
  {
    const int c = t >> 2, rc = (t & 3) * 16;
    unsigned short* dst = out + (size_t)(c0+c)*R + r0 + rc;
    u16x8 o0, o1;
    #pragma unroll
    for (int q=0;q<8;q++){ o0[q] = tile[rc+q][c]; o1[q] = tile[rc+8+q][c]; }
    *(u16x8*)dst       = o0;
    *(u16x8*)(dst + 8) = o1;
  }
}

// ---------------- GEMM v3: m97 tile + TRIPLE-buffer LDS + counted vmcnt (T4) + raw s_barrier,
// ---------------- T2 slot swizzle, T1 XCD swizzle, T5 setprio (r20 measured-best config) ----------------
// C[M,N] = A[M,K] @ Bt[N,K]^T
// MODE 0: bf16 out + bias.   MODE 2: K-split partial (gridDim.z planes), bf16, no bias.
template<int MODE>
__global__ __launch_bounds__(256) void gemm_bt(
    const unsigned short* __restrict__ A, const unsigned short* __restrict__ Bt,
    const float* __restrict__ bias,
    unsigned short* __restrict__ Cbf,
    int M, int N, int K)
{
  __shared__ __align__(16) unsigned short ldsA[3][128*32];
  __shared__ __align__(16) unsigned short ldsB[3][128*32];   // 48 KB
  const int tid  = threadIdx.x;
  const int w    = tid >> 6;
  const int lane = tid & 63;
  const int g    = lane >> 4;
  const int li   = lane & 15;

  // T1: bijective XCD swizzle (per z-plane; nwg % 8 == 0 for all uses)
  const int gx = gridDim.x;
  const int nwg = gx * gridDim.y;
  const int lin = blockIdx.x + gx * blockIdx.y;
  const int q8  = nwg >> 3;
  const int nl  = (lin & 7) * q8 + (lin >> 3);
  const int bm  = (nl % gx) * 128;
  const int bn  = (nl / gx) * 128;

  const int wm   = (w >> 1) * 64;
  const int wn   = (w & 1) * 64;

  const int KS  = (MODE==2) ? (K / (int)gridDim.z) : K;
  const int kt0 = (MODE==2) ? (blockIdx.z * KS) : 0;
  const int nsteps = KS >> 5;

  f32x4 acc[4][4];
  #pragma unroll
  for (int i=0;i<4;i++)
    #pragma unroll
    for (int j=0;j<4;j++)
      acc[i][j] = (f32x4){0.f,0.f,0.f,0.f};

  const int srow = lane >> 2;                                  // 0..15 (row within 16-row chunk)
  const int scb  = ((lane & 3) ^ ((srow >> 1) & 3)) * 16;      // swizzled source col (bytes)
  const int rsw  = (li >> 1) & 3;                              // read-side slot xor

  auto stage = [&](int buf, int step){
    const int kt = kt0 + step*32;
    #pragma unroll
    for (int i=0;i<2;i++){
      const int chunk = i*4 + w;
      const int row   = chunk*16 + srow;
      gload16((const char*)A  + ((size_t)(bm+row)*K + kt)*2 + scb, (char*)ldsA[buf] + chunk*1024);
      gload16((const char*)Bt + ((size_t)(bn+row)*K + kt)*2 + scb, (char*)ldsB[buf] + chunk*1024);
    }
  };

  stage(0, 0);
  stage(1, 1);
  for (int s = 0; s < nsteps; ++s){
    if (s + 1 < nsteps){
      asm volatile("s_waitcnt vmcnt(4)" ::: "memory");
    } else {
      asm volatile("s_waitcnt vmcnt(0)" ::: "memory");
    }
    __builtin_amdgcn_sched_barrier(0);
    __builtin_amdgcn_s_barrier();
    __builtin_amdgcn_sched_barrier(0);
    if (s + 2 < nsteps) stage((s+2)%3, s+2);
    const int cur = s % 3;
    bf16x8 af[4], bfr[4];
    #pragma unroll
    for (int mi=0;mi<4;mi++)
      af[mi] = *(const bf16x8*)((const char*)ldsA[cur] + (wm + mi*16 + li)*64 + ((g ^ rsw)*16));
    #pragma unroll
    for (int ni=0;ni<4;ni++)
      bfr[ni] = *(const bf16x8*)((const char*)ldsB[cur] + (wn + ni*16 + li)*64 + ((g ^ rsw)*16));
    __builtin_amdgcn_s_setprio(1);
    #pragma unroll
    for (int mi=0;mi<4;mi++)
      #pragma unroll
      for (int ni=0;ni<4;ni++)
        mfma16(af[mi], bfr[ni], acc[mi][ni]);
    __builtin_amdgcn_s_setprio(0);
  }

  const size_t zoff = (MODE==2) ? ((size_t)blockIdx.z * M * N) : 0;
  #pragma unroll
  for (int ni=0;ni<4;ni++){
    const int col = bn + wn + ni*16 + li;
    const float bv = (MODE==0) ? bias[col] : 0.f;
    #pragma unroll
    for (int mi=0;mi<4;mi++){
      #pragma unroll
      for (int r=0;r<4;r++){
        const int row = bm + wm + mi*16 + g*4 + r;
        Cbf[zoff + (size_t)row*N + col] = f2bf(acc[mi][ni][r] + bv);
      }
    }
  }
}

// ---------------- out-proj epilogue: out = residual + (p0 + p1 + bias) * gate_mod ----------------
// partials are bf16 planes (4 elements = uint2 per thread-quad)
__global__ __launch_bounds__(256) void out_combine_kernel(
    const unsigned short* __restrict__ part, const float* __restrict__ bias,
    const float* __restrict__ residual, const float* __restrict__ gate_mod,
    float* __restrict__ out)
{
  const size_t idx = (size_t)blockIdx.x*256 + threadIdx.x;      // 4-element index
  const int col4 = (int)(idx & (DIMSZ/4 - 1));
  const uint2 ua = ((const uint2*)part)[idx];
  const uint2 ub = ((const uint2*)part)[idx + (size_t)TOK*DIMSZ/4];
  const float4 r = ((const float4*)residual)[idx];
  const float4 bv = ((const float4*)bias)[col4];
  const float4 gm = ((const float4*)gate_mod)[col4];
  float4 o;
  o.x = r.x + (bf2f((unsigned short)ua.x)       + bf2f((unsigned short)ub.x)       + bv.x) * gm.x;
  o.y = r.y + (bf2f((unsigned short)(ua.x>>16)) + bf2f((unsigned short)(ub.x>>16)) + bv.y) * gm.y;
  o.z = r.z + (bf2f((unsigned short)ua.y)       + bf2f((unsigned short)ub.y)       + bv.z) * gm.z;
  o.w = r.w + (bf2f((unsigned short)(ua.y>>16)) + bf2f((unsigned short)(ub.y>>16)) + bv.w) * gm.w;
  ((float4*)out)[idx] = o;
}

// ---------------- RMSNorm + RoPE; Q scaled by (1/8)*log2(e) so softmax runs in exp2 domain ----------------
__global__ __launch_bounds__(256) void norm_rope_kernel(
    const unsigned short* __restrict__ qkv,
    const float* __restrict__ nqw, const float* __restrict__ nkw,
    const float* __restrict__ rc, const float* __restrict__ rsn,
    unsigned short* __restrict__ Q, unsigned short* __restrict__ Ko)
{
  const int n = blockIdx.x, t = threadIdx.x;
  __shared__ float red[2][4];
  #pragma unroll
  for (int qk=0; qk<2; qk++){
    const unsigned short* row = qkv + (size_t)n*D3 + qk*DIMSZ;
    u16x8 v = *(const u16x8*)(row + t*8);
    float f[8]; float ss = 0.f;
    #pragma unroll
    for (int j=0;j<8;j++){ f[j] = bf2f(v[j]); ss += f[j]*f[j]; }
    #pragma unroll
    for (int msk=1; msk<64; msk<<=1) ss += __shfl_xor(ss, msk);
    if ((t&63)==0) red[qk][t>>6] = ss;
    __syncthreads();
    const float rs = rsqrtf((red[qk][0]+red[qk][1]+red[qk][2]+red[qk][3]) * (1.0f/2048.f) + 1e-6f);
    const int d = t*8, hd = d&63, h = d>>6;
    const int pd = (hd<32) ? d+32 : d-32;
    u16x8 pv = *(const u16x8*)(row + pd);
    const float* wv = qk ? nkw : nqw;
    const float4 wv0 = *(const float4*)(wv + d),      wv1 = *(const float4*)(wv + d + 4);
    const float4 pw0 = *(const float4*)(wv + pd),     pw1 = *(const float4*)(wv + pd + 4);
    const float4 cs0 = *(const float4*)(rc + n*64 + hd),  cs1 = *(const float4*)(rc + n*64 + hd + 4);
    const float4 sn0 = *(const float4*)(rsn + n*64 + hd), sn1 = *(const float4*)(rsn + n*64 + hd + 4);
    const float wvv[8] = {wv0.x,wv0.y,wv0.z,wv0.w, wv1.x,wv1.y,wv1.z,wv1.w};
    const float pwv[8] = {pw0.x,pw0.y,pw0.z,pw0.w, pw1.x,pw1.y,pw1.z,pw1.w};
    const float csv[8] = {cs0.x,cs0.y,cs0.z,cs0.w, cs1.x,cs1.y,cs1.z,cs1.w};
    const float snv[8] = {sn0.x,sn0.y,sn0.z,sn0.w, sn1.x,sn1.y,sn1.z,sn1.w};
    const float scl = qk ? 1.f : (0.125f * 1.44269504088896340736f);
    const float sgn = (hd<32) ? -1.f : 1.f;
    u16x8 ov;
    #pragma unroll
    for (int j=0;j<8;j++){
      const float a = f[j]*rs*wvv[j];
      const float b = bf2f(pv[j])*rs*pwv[j];
      ov[j] = f2bf((a*csv[j] + sgn*b*snv[j])*scl);
    }
    unsigned short* dst = (qk ? Ko : Q) + ((size_t)h*TOK + n)*HDIM + hd;
    *(u16x8*)dst = ov;
  }
}

// ---------------- V transpose per head: qkv v-part (N,HD slice) -> Vt (H,HD,N) ----------------
__global__ __launch_bounds__(256) void v_transpose_kernel(
    const unsigned short* __restrict__ qkv, unsigned short* __restrict__ Vt){
  const int h = blockIdx.y, n0 = blockIdx.x*64;
  __shared__ unsigned short tile[64][65];
  const int t = threadIdx.x;
  const int i = t>>2, j0 = (t&3)*16;
  const unsigned short* src = qkv + (size_t)(n0+i)*D3 + 2*DIMSZ + h*HDIM + j0;
  #pragma unroll
  for (int q=0;q<16;q++) tile[i][j0+q] = src[q];
  __syncthreads();
  unsigned short* dst = Vt + ((size_t)h*HDIM + i)*TOK + n0 + j0;
  #pragma unroll
  for (int q=0;q<16;q++) dst[q] = tile[j0+q][i];
}

// ---------------- Flash attention: KV-split-2, NO max tracking, launch_bounds(256,4) ----------------
__global__ __launch_bounds__(256, 4) void flash_kernel(
    const unsigned short* __restrict__ Q, const unsigned short* __restrict__ K,
    const unsigned short* __restrict__ Vt,
    unsigned short* __restrict__ Opart, float* __restrict__ lpart)
{
  __shared__ __align__(16) unsigned short ldsK[2][64*64];
  __shared__ __align__(16) unsigned short ldsV[2][64*64];
  const int tid = threadIdx.x;
  const int w = tid >> 6, lane = tid & 63;
  const int q5 = lane & 31, hi = lane >> 5;
  const int sp = blockIdx.y & (NSPLIT-1), h = blockIdx.y >> 1;
  const int q0 = blockIdx.x * 128;
  const int qrow = q0 + w*32 + q5;
  const int kt0 = sp * KVCHUNK;

  const unsigned short* Qh = Q + (size_t)h*TOK*HDIM;
  bf16x8 qf[4];
  #pragma unroll
  for (int ks=0; ks<4; ks++)
    qf[ks] = *(const bf16x8*)(Qh + (size_t)qrow*HDIM + ks*16 + hi*8);

  f32x16 o0 = {}, o1 = {};
  float l_ = 0.f;

  const char* Kh = (const char*)(K  + (size_t)h*TOK*HDIM);   // 128B rows
  const char* Vh = (const char*)(Vt + (size_t)h*HDIM*TOK);   // 4096B rows
  const int srow = lane >> 3;                  // staging row mod 8
  const int scb  = ((lane & 7) ^ srow) * 16;   // pre-swizzled source column
  const int xr   = (lane & 7) << 4;            // read-side xor (row&7 == lane&7)

  auto stage = [&](int buf, int kt){
    #pragma unroll
    for (int i=0;i<2;i++){
      const int chunk = i*4 + w;
      const int row = chunk*8 + srow;
      gload16(Kh + (size_t)(kt+row)*128 + scb, (char*)ldsK[buf] + chunk*1024);
      gload16(Vh + (size_t)row*4096 + (size_t)kt*2 + scb, (char*)ldsV[buf] + chunk*1024);
    }
  };

  stage(0, kt0);
  int cur = 0;
  for (int kt = kt0; kt < kt0 + KVCHUNK; kt += 64){
    __syncthreads();
    if (kt + 64 < kt0 + KVCHUNK) stage(cur^1, kt + 64);

    f32x16 s0 = {}, s1 = {};
    __builtin_amdgcn_s_setprio(1);
    #pragma unroll
    for (int ks=0; ks<4; ks++){
      const int cb = (ks*32 + hi*16) ^ xr;
      const bf16x8 kb0 = *(const bf16x8*)((const char*)ldsK[cur] + q5*128 + cb);
      const bf16x8 kb1 = *(const bf16x8*)((const char*)ldsK[cur] + (32+q5)*128 + cb);
      mfma32(kb0, qf[ks], s0);
      mfma32(kb1, qf[ks], s1);
    }
    __builtin_amdgcn_s_setprio(0);

    // P = exp2(S) directly (no running max); lane-local l accumulation
    unsigned pw[16];
    #pragma unroll
    for (int i=0;i<8;i++){
      const float pa = exp2f(s0[2*i]);
      const float pb = exp2f(s0[2*i+1]);
      l_ += pa + pb;
      pw[i] = pack2bf(pa, pb);
    }
    #pragma unroll
    for (int i=0;i<8;i++){
      const float pa = exp2f(s1[2*i]);
      const float pb = exp2f(s1[2*i+1]);
      l_ += pa + pb;
      pw[8+i] = pack2bf(pa, pb);
    }

    __builtin_amdgcn_s_setprio(1);
    #pragma unroll
    for (int ks2=0; ks2<4; ks2++){
      const int b = 4*ks2;
      const uint2v r0 = plswap(pw[b],   pw[b+2]);
      const uint2v r1 = plswap(pw[b+1], pw[b+3]);
      union { unsigned u[4]; bf16x8 v; } pf;
      pf.u[0] = r0[0]; pf.u[1] = r1[0]; pf.u[2] = r0[1]; pf.u[3] = r1[1];
      const int cb = (ks2*32 + hi*16) ^ xr;
      const bf16x8 vb0 = *(const bf16x8*)((const char*)ldsV[cur] + q5*128 + cb);
      const bf16x8 vb1 = *(const bf16x8*)((const char*)ldsV[cur] + (32+q5)*128 + cb);
      mfma32(vb0, pf.v, o0);
      mfma32(vb1, pf.v, o1);
    }
    __builtin_amdgcn_s_setprio(0);
    cur ^= 1;
  }

  const float lt = l_ + __shfl_xor(l_, 32);
  const size_t prow = ((size_t)(sp*NHEAD + h)*TOK + qrow);
  if (hi == 0) lpart[prow] = lt;
  unsigned short* orow = Opart + prow*HDIM;
  #pragma unroll
  for (int j=0;j<4;j++){
    const int d0 = 8*j + 4*hi;
    uint2 v0, v1;
    v0.x = pack2bf(o0[4*j],   o0[4*j+1]);
    v0.y = pack2bf(o0[4*j+2], o0[4*j+3]);
    v1.x = pack2bf(o1[4*j],   o1[4*j+1]);
    v1.y = pack2bf(o1[4*j+2], o1[4*j+3]);
    *(uint2*)(orow + d0)      = v0;
    *(uint2*)(orow + 32 + d0) = v1;
  }
}

// ---------------- split combine (2 splits, no-max: plain sums) ----------------
__global__ __launch_bounds__(256) void combine_kernel(
    const unsigned short* __restrict__ Opart, const float* __restrict__ lpart,
    const float* __restrict__ gate, unsigned short* __restrict__ attn_out)
{
  const int tid = threadIdx.x;
  const int R = blockIdx.x*8 + (tid >> 5);       // (h, q) row index
  const int l32 = tid & 31;                      // element pair index
  const int h = R >> 11, q = R & (TOK-1);

  const float* lp = lpart + (size_t)h*TOK + q;
  const size_t lstr = (size_t)NHEAD*TOK;
  const float L = lp[0] + lp[lstr];

  const unsigned* Op = (const unsigned*)Opart;
  const size_t b32 = ((size_t)h*TOK + q)*32 + l32;
  const size_t str = (size_t)NHEAD*TOK*32;
  const unsigned u0 = Op[b32], u1 = Op[b32+str];

  const float oa = bf2f((unsigned short)u0) + bf2f((unsigned short)u1);
  const float ob = bf2f((unsigned short)(u0>>16)) + bf2f((unsigned short)(u1>>16));

  const float gv = gate[(size_t)h*TOK + q];
  const float sc = gv / L;
  const unsigned word = (unsigned)f2bf(oa*sc) | ((unsigned)f2bf(ob*sc) << 16);
  *(unsigned*)(attn_out + (size_t)q*DIMSZ + h*HDIM + l32*2) = word;
}

// ---------------- launch ----------------

extern "C" void kernel_launch(void* const* d_in, const int* in_sizes, int n_in,
                              void* d_out, int out_size, void* d_ws, size_t ws_size,
                              hipStream_t stream)
{
  const float* x        = (const float*)d_in[0];
  const float* W_qkv    = (const float*)d_in[1];
  const float* b_qkv    = (const float*)d_in[2];
  const float* nq_w     = (const float*)d_in[3];
  const float* nk_w     = (const float*)d_in[4];
  const float* W_gate   = (const float*)d_in[5];
  const float* b_gate   = (const float*)d_in[6];
  const float* W_out    = (const float*)d_in[7];
  const float* b_out    = (const float*)d_in[8];
  const float* rope_cos = (const float*)d_in[9];
  const float* rope_sin = (const float*)d_in[10];
  const float* residual = (const float*)d_in[11];
  const float* gate_mod = (const float*)d_in[12];
  float* out = (float*)d_out;

  char* p = (char*)d_ws;
  auto take = [&](size_t b)->char*{ char* q = p; p += (b + 255) & ~(size_t)255; return q; };
  unsigned short* x_bf   = (unsigned short*)take((size_t)TOK*DIMSZ*2);
  unsigned short* WqkvT  = (unsigned short*)take((size_t)D3*DIMSZ*2);
  unsigned short* WoutT  = (unsigned short*)take((size_t)DIMSZ*DIMSZ*2);
  unsigned short* qkv    = (unsigned short*)take((size_t)TOK*D3*2);
  unsigned short* Qb     = (unsigned short*)take((size_t)NHEAD*TOK*HDIM*2);
  unsigned short* Kb     = (unsigned short*)take((size_t)NHEAD*TOK*HDIM*2);
  unsigned short* Vtb    = (unsigned short*)take((size_t)NHEAD*HDIM*TOK*2);
  unsigned short* attn_g = (unsigned short*)take((size_t)TOK*DIMSZ*2);
  float*          gateb  = (float*)take((size_t)NHEAD*TOK*4);
  unsigned short* Opart  = (unsigned short*)take((size_t)NSPLIT*NHEAD*TOK*HDIM*2);
  float*          lpart  = (float*)take((size_t)NSPLIT*NHEAD*TOK*4);
  // out-proj K-split bf16 partials (2 x M x N x 2B = 16.8 MB) reuse Opart's space
  // (NSPLIT=2 Opart is exactly 16.8 MB; dead after combine_kernel).
  unsigned short* oproj  = Opart;

  gate_kernel<<<TOK, 256, 0, stream>>>(x, W_gate, b_gate, gateb, x_bf);
  transpose_cvt_kernel<<<dim3(DIMSZ/64, D3/64),   256, 0, stream>>>(W_qkv, WqkvT, DIMSZ, D3);
  transpose_cvt_kernel<<<dim3(DIMSZ/64, DIMSZ/64),256, 0, stream>>>(W_out, WoutT, DIMSZ, DIMSZ);
  gemm_bt<0><<<dim3(TOK/128, D3/128), 256, 0, stream>>>(
      x_bf, WqkvT, b_qkv, qkv, TOK, D3, DIMSZ);
  norm_rope_kernel<<<TOK, 256, 0, stream>>>(qkv, nq_w, nk_w, rope_cos, rope_sin, Qb, Kb);
  v_transpose_kernel<<<dim3(TOK/64, NHEAD), 256, 0, stream>>>(qkv, Vtb);
  flash_kernel<<<dim3(TOK/128, NHEAD*NSPLIT), 256, 0, stream>>>(Qb, Kb, Vtb, Opart, lpart);
  combine_kernel<<<NHEAD*TOK/8, 256, 0, stream>>>(Opart, lpart, gateb, attn_g);
  gemm_bt<2><<<dim3(TOK/128, DIMSZ/128, 2), 256, 0, stream>>>(
      attn_g, WoutT, b_out, oproj, TOK, DIMSZ, DIMSZ);
  out_combine_kernel<<<TOK*DIMSZ/1024, 256, 0, stream>>>(
      oproj, b_out, residual, gate_mod, out);
}